// Round 3
// baseline (301.331 us; speedup 1.0000x reference)
//
#include <hip/hip_runtime.h>
#include <cstdint>

#define B_ 2
#define L_ 2048
#define D_ 1024
#define H_ 16
#define HD_ 64
#define ML_ (B_ * L_)  // 4096 token rows
#define S_ (3 * D_)    // fused qkv output width (N of QKV GEMM)
#define QK_LD 2048     // row stride of the Q|K buffer (V goes to Vt instead)

typedef __bf16 bf16;
typedef __attribute__((ext_vector_type(4))) __bf16 bf16x4;
typedef __attribute__((ext_vector_type(8))) __bf16 bf16x8;
typedef __attribute__((ext_vector_type(4))) float f32x4;

__device__ __forceinline__ f32x4 mfma_16x16x32(bf16x8 a, bf16x8 b, f32x4 c) {
    return __builtin_amdgcn_mfma_f32_16x16x32_bf16(a, b, c, 0, 0, 0);
}

#define GLDS16(g, l)                                                              \
    __builtin_amdgcn_global_load_lds((const __attribute__((address_space(1))) void*)(g), \
                                     (__attribute__((address_space(3))) void*)(l), 16, 0, 0)

// ---------------- cast x: fp32 -> bf16, 4 elems/thread ----------------
__global__ __launch_bounds__(256) void cast_x_kernel(const float* __restrict__ in,
                                                     bf16* __restrict__ out, int n4) {
    int i = blockIdx.x * blockDim.x + threadIdx.x;
    if (i >= n4) return;
    float4 v = reinterpret_cast<const float4*>(in)[i];
    bf16x4 o;
    o[0] = (bf16)v.x; o[1] = (bf16)v.y; o[2] = (bf16)v.z; o[3] = (bf16)v.w;
    reinterpret_cast<bf16x4*>(out)[i] = o;
}

// ------------- transpose + cast weight: W[k][n] fp32 -> Wt[n][k] bf16 -------------
__global__ __launch_bounds__(1024) void transpose_w_kernel(const float* __restrict__ W,
                                                           bf16* __restrict__ Wt) {
    __shared__ float tile[32][33];
    int n0 = blockIdx.x * 32, k0 = blockIdx.y * 32;
    int tx = threadIdx.x, ty = threadIdx.y;
    tile[ty][tx] = W[(size_t)(k0 + ty) * D_ + n0 + tx];
    __syncthreads();
    Wt[(size_t)(n0 + ty) * D_ + k0 + tx] = (bf16)tile[tx][ty];
}

// ------------- GEMM m97-style: 128x128 tile, global_load_lds width=16 -------------
// C[M,N] = A[M,K] @ Bt[N,K]^T.  Output goes to C (row stride ldc) for tile cols
// < 2048, or (if vt != nullptr) transposed into vt[b][h][hd][L] for cols >= 2048
// (the V part of the fused QKV projection).
template <typename OutT>
__global__ __launch_bounds__(256) void gemm128_kernel(const bf16* __restrict__ A,
                                                      const bf16* __restrict__ Bt,
                                                      OutT* __restrict__ C,
                                                      bf16* __restrict__ vt,
                                                      int M, int N, int K, int ldc) {
    __shared__ bf16 As[128][32];  // linear: global_load_lds needs contiguous dest
    __shared__ bf16 Bs[128][32];
    const int nb = N >> 7;
    const int bm = blockIdx.x / nb, bn = blockIdx.x % nb;
    const int m0 = bm << 7, n0 = bn << 7;
    const int t = threadIdx.x;
    const int lane = t & 63;
    const int w = t >> 6;
    const int wm = w >> 1, wn = w & 1;
    const int fr = lane & 15, fk = (lane >> 4) << 3;
    const int srow = (w << 5) + (lane >> 2);
    const int scol = (lane & 3) << 3;

    f32x4 acc[4][4] = {};
    for (int k0 = 0; k0 < K; k0 += 32) {
        const bf16* ga0 = &A[(size_t)(m0 + srow) * K + k0 + scol];
        const bf16* ga1 = &A[(size_t)(m0 + srow + 16) * K + k0 + scol];
        const bf16* gb0 = &Bt[(size_t)(n0 + srow) * K + k0 + scol];
        const bf16* gb1 = &Bt[(size_t)(n0 + srow + 16) * K + k0 + scol];
        __syncthreads();
        GLDS16(ga0, &As[(w << 5)][0]);
        GLDS16(ga1, &As[(w << 5) + 16][0]);
        GLDS16(gb0, &Bs[(w << 5)][0]);
        GLDS16(gb1, &Bs[(w << 5) + 16][0]);
        __syncthreads();
        bf16x8 a[4], b[4];
#pragma unroll
        for (int mt = 0; mt < 4; ++mt)
            a[mt] = *reinterpret_cast<const bf16x8*>(&As[(wm << 6) + (mt << 4) + fr][fk]);
#pragma unroll
        for (int nt = 0; nt < 4; ++nt)
            b[nt] = *reinterpret_cast<const bf16x8*>(&Bs[(wn << 6) + (nt << 4) + fr][fk]);
#pragma unroll
        for (int mt = 0; mt < 4; ++mt)
#pragma unroll
            for (int nt = 0; nt < 4; ++nt)
                acc[mt][nt] = mfma_16x16x32(a[mt], b[nt], acc[mt][nt]);
    }
    const int col = lane & 15, rq = (lane >> 4) << 2;
    if (vt != nullptr && n0 >= 2048) {
        // V region: write transposed -> vt[((b*H + h)*HD + hd)][l], 4 tokens packed
#pragma unroll
        for (int mt = 0; mt < 4; ++mt)
#pragma unroll
            for (int nt = 0; nt < 4; ++nt) {
                int cc = n0 - 2048 + (wn << 6) + (nt << 4) + col;  // 0..1023
                int rrb = m0 + (wm << 6) + (mt << 4) + rq;
                int bb = rrb >> 11, l = rrb & (L_ - 1);
                size_t vrow = ((size_t)bb * H_ + (cc >> 6)) * HD_ + (cc & 63);
                bf16x4 pk;
#pragma unroll
                for (int reg = 0; reg < 4; ++reg) pk[reg] = (bf16)acc[mt][nt][reg];
                *reinterpret_cast<bf16x4*>(&vt[vrow * L_ + l]) = pk;
            }
    } else {
#pragma unroll
        for (int mt = 0; mt < 4; ++mt)
#pragma unroll
            for (int nt = 0; nt < 4; ++nt)
#pragma unroll
                for (int reg = 0; reg < 4; ++reg) {
                    int rr = m0 + (wm << 6) + (mt << 4) + rq + reg;
                    int cc = n0 + (wn << 6) + (nt << 4) + col;
                    C[(size_t)rr * ldc + cc] = (OutT)acc[mt][nt][reg];
                }
    }
}

// ------------- causal flash attention v3: barrier-free, global-direct K/V -------------
// qk:  [B*L][2048]  (Q at col 0, K at col 1024; head h at +h*64)
// vt:  [B][H][HD][L]  (V transposed, written by the QKV GEMM epilogue)
// O:   [B*L][1024]
__global__ __launch_bounds__(256) void attn_kernel(const bf16* __restrict__ qk,
                                                   const bf16* __restrict__ vt,
                                                   bf16* __restrict__ O) {
    __shared__ bf16 P_lds[4][16][72];  // per-wave P tile [qrow16][kv64]
    const int nqt = L_ / 64;           // 32
    const int nbh = B_ * H_;           // 32
    // LPT order: heavy q-tiles (large qt) dispatch first; 32 consecutive ids share qt
    const int qt = nqt - 1 - (int)(blockIdx.x / nbh);
    const int bh = blockIdx.x % nbh;
    const int h = bh % H_, b = bh / H_;
    const int t = threadIdx.x;
    const int lane = t & 63, w = t >> 6;
    const int lr = lane & 15, lg = lane >> 4;
    const int qr0 = qt * 64;

    const bf16* kbase = qk + (size_t)b * L_ * QK_LD + D_ + h * HD_;  // K rows, stride QK_LD
    const bf16* vbase = vt + (size_t)bh * HD_ * L_;                  // Vt rows, stride L_

    // Q fragments (A-operand): row = w*16+lr, k(hd) = lg*8+i; two K=32 halves
    const bf16* qp = qk + (size_t)(b * L_ + qr0 + w * 16 + lr) * QK_LD + h * HD_ + (lg << 3);
    bf16x8 qf0 = *reinterpret_cast<const bf16x8*>(qp);
    bf16x8 qf1 = *reinterpret_cast<const bf16x8*>(qp + 32);

    f32x4 o[4] = {};
    float mrun[4] = {-1e30f, -1e30f, -1e30f, -1e30f};
    float lsum[4] = {};
    const int qrow = qr0 + w * 16 + (lg << 2);

    for (int kb = 0; kb <= qt; ++kb) {
        const int c0 = kb * 64;
        // QK^T: s[sub] covers kv cols c0+sub*16..+16; K direct from global (L2)
        f32x4 s[4] = {};
        __builtin_amdgcn_s_setprio(1);
#pragma unroll
        for (int sub = 0; sub < 4; ++sub) {
            const bf16* kp = kbase + (size_t)(c0 + (sub << 4) + lr) * QK_LD + (lg << 3);
            bf16x8 kf0 = *reinterpret_cast<const bf16x8*>(kp);
            bf16x8 kf1 = *reinterpret_cast<const bf16x8*>(kp + 32);
            s[sub] = mfma_16x16x32(qf0, kf0, s[sub]);
            s[sub] = mfma_16x16x32(qf1, kf1, s[sub]);
        }
        __builtin_amdgcn_s_setprio(0);
        // online softmax: D layout col=lr (kv within sub), row=lg*4+reg (q within 16)
#pragma unroll
        for (int reg = 0; reg < 4; ++reg) {
            const int row = qrow + reg;
            float vv[4];
            float rm = -1e30f;
#pragma unroll
            for (int sub = 0; sub < 4; ++sub) {
                vv[sub] = (c0 + (sub << 4) + lr <= row) ? s[sub][reg] * 0.125f : -1e30f;
                rm = fmaxf(rm, vv[sub]);
            }
            rm = fmaxf(rm, __shfl_xor(rm, 1));
            rm = fmaxf(rm, __shfl_xor(rm, 2));
            rm = fmaxf(rm, __shfl_xor(rm, 4));
            rm = fmaxf(rm, __shfl_xor(rm, 8));
            const float mn = fmaxf(mrun[reg], rm);
            float rs = 0.f;
#pragma unroll
            for (int sub = 0; sub < 4; ++sub) {
                float p = __expf(vv[sub] - mn);
                rs += p;
                P_lds[w][(lg << 2) + reg][(sub << 4) + lr] = (bf16)p;
            }
            rs += __shfl_xor(rs, 1);
            rs += __shfl_xor(rs, 2);
            rs += __shfl_xor(rs, 4);
            rs += __shfl_xor(rs, 8);
            const float sc = __expf(mrun[reg] - mn);
            lsum[reg] = lsum[reg] * sc + rs;
            mrun[reg] = mn;
#pragma unroll
            for (int nt = 0; nt < 4; ++nt) o[nt][reg] *= sc;
        }
        // P_lds is per-wave: in-wave lgkmcnt ordering suffices, NO barrier.
        bf16x8 pa0 = *reinterpret_cast<const bf16x8*>(&P_lds[w][lr][lg << 3]);
        bf16x8 pa1 = *reinterpret_cast<const bf16x8*>(&P_lds[w][lr][32 + (lg << 3)]);
        // PV: B-fragments contiguous from vt (L2)
        __builtin_amdgcn_s_setprio(1);
#pragma unroll
        for (int nt = 0; nt < 4; ++nt) {
            const bf16* vp = vbase + (size_t)((nt << 4) + lr) * L_ + c0 + (lg << 3);
            bf16x8 vf0 = *reinterpret_cast<const bf16x8*>(vp);
            bf16x8 vf1 = *reinterpret_cast<const bf16x8*>(vp + 32);
            o[nt] = mfma_16x16x32(pa0, vf0, o[nt]);
            o[nt] = mfma_16x16x32(pa1, vf1, o[nt]);
        }
        __builtin_amdgcn_s_setprio(0);
    }
    float rinv[4];
#pragma unroll
    for (int reg = 0; reg < 4; ++reg) rinv[reg] = 1.0f / lsum[reg];
#pragma unroll
    for (int nt = 0; nt < 4; ++nt)
#pragma unroll
        for (int reg = 0; reg < 4; ++reg)
            O[((size_t)b * L_ + qrow + reg) * D_ + h * HD_ + (nt << 4) + lr] =
                (bf16)(o[nt][reg] * rinv[reg]);
}

extern "C" void kernel_launch(void* const* d_in, const int* in_sizes, int n_in,
                              void* d_out, int out_size, void* d_ws, size_t ws_size,
                              hipStream_t stream) {
    // setup_inputs dict order: x, Wk, Wq, Wv, Wo
    const float* x = (const float*)d_in[0];
    const float* Wk = (const float*)d_in[1];
    const float* Wq = (const float*)d_in[2];
    const float* Wv = (const float*)d_in[3];
    const float* Wo = (const float*)d_in[4];
    float* out = (float*)d_out;

    char* p = (char*)d_ws;
    const size_t xsz = (size_t)ML_ * D_ * sizeof(bf16);   // 8 MB
    const size_t wsz = (size_t)D_ * D_ * sizeof(bf16);    // 2 MB
    bf16* xb = (bf16*)p;   p += xsz;                      // x bf16 [4096][1024]
    bf16* Wc = (bf16*)p;   p += 3 * wsz;                  // [Wq^T; Wk^T; Wv^T] rows
    bf16* Wot = (bf16*)p;  p += wsz;
    bf16* qkb = (bf16*)p;  p += (size_t)ML_ * QK_LD * sizeof(bf16);  // [4096][2048] Q|K
    bf16* vtb = (bf16*)p;  p += xsz;                      // [B][H][HD][L] = 8 MB
    bf16* ab = xb;  // attn output reuses x buffer (x dead after qkv GEMM)

    const int n4 = ML_ * D_ / 4;
    cast_x_kernel<<<(n4 + 255) / 256, 256, 0, stream>>>(x, xb, n4);
    dim3 tb(32, 32);
    dim3 tg(D_ / 32, D_ / 32);
    transpose_w_kernel<<<tg, tb, 0, stream>>>(Wq, Wc);
    transpose_w_kernel<<<tg, tb, 0, stream>>>(Wk, Wc + (size_t)D_ * D_);
    transpose_w_kernel<<<tg, tb, 0, stream>>>(Wv, Wc + 2 * (size_t)D_ * D_);
    transpose_w_kernel<<<tg, tb, 0, stream>>>(Wo, Wot);

    // fused QKV projection: Q,K -> qkb (stride 2048); V -> vtb transposed
    gemm128_kernel<bf16><<<(ML_ / 128) * (S_ / 128), 256, 0, stream>>>(
        xb, Wc, qkb, vtb, ML_, S_, D_, QK_LD);

    attn_kernel<<<B_ * H_ * (L_ / 64), 256, 0, stream>>>(qkb, vtb, ab);

    // output projection -> fp32 out
    gemm128_kernel<float><<<(ML_ / 128) * (D_ / 128), 256, 0, stream>>>(
        ab, Wot, out, nullptr, ML_, D_, D_, D_);
}

// Round 5
// 253.276 us; speedup vs baseline: 1.1897x; 1.1897x over previous
//
#include <hip/hip_runtime.h>
#include <cstdint>

#define B_ 2
#define L_ 2048
#define D_ 1024
#define H_ 16
#define HD_ 64
#define ML_ (B_ * L_)  // 4096 token rows
#define S_ (3 * D_)    // fused qkv output width (N of QKV GEMM)
#define QK_LD 2048     // row stride of the Q|K buffer (V goes to Vt instead)

typedef __bf16 bf16;
typedef __attribute__((ext_vector_type(4))) __bf16 bf16x4;
typedef __attribute__((ext_vector_type(8))) __bf16 bf16x8;
typedef __attribute__((ext_vector_type(4))) float f32x4;
typedef __attribute__((ext_vector_type(16))) float f32x16;

__device__ __forceinline__ f32x4 mfma_16x16x32(bf16x8 a, bf16x8 b, f32x4 c) {
    return __builtin_amdgcn_mfma_f32_16x16x32_bf16(a, b, c, 0, 0, 0);
}
__device__ __forceinline__ f32x16 mfma_32x32x16(bf16x8 a, bf16x8 b, f32x16 c) {
    return __builtin_amdgcn_mfma_f32_32x32x16_bf16(a, b, c, 0, 0, 0);
}

#define GLDS16(g, l)                                                              \
    __builtin_amdgcn_global_load_lds((const __attribute__((address_space(1))) void*)(g), \
                                     (__attribute__((address_space(3))) void*)(l), 16, 0, 0)

// ---------------- cast x: fp32 -> bf16, 4 elems/thread ----------------
__global__ __launch_bounds__(256) void cast_x_kernel(const float* __restrict__ in,
                                                     bf16* __restrict__ out, int n4) {
    int i = blockIdx.x * blockDim.x + threadIdx.x;
    if (i >= n4) return;
    float4 v = reinterpret_cast<const float4*>(in)[i];
    bf16x4 o;
    o[0] = (bf16)v.x; o[1] = (bf16)v.y; o[2] = (bf16)v.z; o[3] = (bf16)v.w;
    reinterpret_cast<bf16x4*>(out)[i] = o;
}

// ------------- transpose + cast weight: W[k][n] fp32 -> Wt[n][k] bf16 -------------
__global__ __launch_bounds__(1024) void transpose_w_kernel(const float* __restrict__ W,
                                                           bf16* __restrict__ Wt) {
    __shared__ float tile[32][33];
    int n0 = blockIdx.x * 32, k0 = blockIdx.y * 32;
    int tx = threadIdx.x, ty = threadIdx.y;
    tile[ty][tx] = W[(size_t)(k0 + ty) * D_ + n0 + tx];
    __syncthreads();
    Wt[(size_t)(n0 + ty) * D_ + k0 + tx] = (bf16)tile[tx][ty];
}

// ------------- GEMM m97-style: 128x128 tile, global_load_lds width=16 -------------
// C[M,N] = A[M,K] @ Bt[N,K]^T.  V-region tiles (cols >= 2048 when vt != nullptr)
// are written transposed into vt[b][h][hd][L].
template <typename OutT>
__global__ __launch_bounds__(256) void gemm128_kernel(const bf16* __restrict__ A,
                                                      const bf16* __restrict__ Bt,
                                                      OutT* __restrict__ C,
                                                      bf16* __restrict__ vt,
                                                      int M, int N, int K, int ldc) {
    __shared__ bf16 As[128][32];
    __shared__ bf16 Bs[128][32];
    // bijective XCD swizzle (grid % 8 == 0 for all our launches)
    const int nwg = gridDim.x;
    const int bid = (blockIdx.x & 7) * (nwg >> 3) + (blockIdx.x >> 3);
    const int nb = N >> 7;
    const int bm = bid / nb, bn = bid % nb;
    const int m0 = bm << 7, n0 = bn << 7;
    const int t = threadIdx.x;
    const int lane = t & 63;
    const int w = t >> 6;
    const int wm = w >> 1, wn = w & 1;
    const int fr = lane & 15, fk = (lane >> 4) << 3;
    const int srow = (w << 5) + (lane >> 2);
    const int scol = (lane & 3) << 3;

    f32x4 acc[4][4] = {};
    for (int k0 = 0; k0 < K; k0 += 32) {
        const bf16* ga0 = &A[(size_t)(m0 + srow) * K + k0 + scol];
        const bf16* ga1 = &A[(size_t)(m0 + srow + 16) * K + k0 + scol];
        const bf16* gb0 = &Bt[(size_t)(n0 + srow) * K + k0 + scol];
        const bf16* gb1 = &Bt[(size_t)(n0 + srow + 16) * K + k0 + scol];
        __syncthreads();
        GLDS16(ga0, &As[(w << 5)][0]);
        GLDS16(ga1, &As[(w << 5) + 16][0]);
        GLDS16(gb0, &Bs[(w << 5)][0]);
        GLDS16(gb1, &Bs[(w << 5) + 16][0]);
        __syncthreads();
        bf16x8 a[4], b[4];
#pragma unroll
        for (int mt = 0; mt < 4; ++mt)
            a[mt] = *reinterpret_cast<const bf16x8*>(&As[(wm << 6) + (mt << 4) + fr][fk]);
#pragma unroll
        for (int nt = 0; nt < 4; ++nt)
            b[nt] = *reinterpret_cast<const bf16x8*>(&Bs[(wn << 6) + (nt << 4) + fr][fk]);
#pragma unroll
        for (int mt = 0; mt < 4; ++mt)
#pragma unroll
            for (int nt = 0; nt < 4; ++nt)
                acc[mt][nt] = mfma_16x16x32(a[mt], b[nt], acc[mt][nt]);
    }
    const int col = lane & 15, rq = (lane >> 4) << 2;
    if (vt != nullptr && n0 >= 2048) {
#pragma unroll
        for (int mt = 0; mt < 4; ++mt)
#pragma unroll
            for (int nt = 0; nt < 4; ++nt) {
                int cc = n0 - 2048 + (wn << 6) + (nt << 4) + col;  // 0..1023
                int rrb = m0 + (wm << 6) + (mt << 4) + rq;
                int bb = rrb >> 11, l = rrb & (L_ - 1);
                size_t vrow = ((size_t)bb * H_ + (cc >> 6)) * HD_ + (cc & 63);
                bf16x4 pk;
#pragma unroll
                for (int reg = 0; reg < 4; ++reg) pk[reg] = (bf16)acc[mt][nt][reg];
                *reinterpret_cast<bf16x4*>(&vt[vrow * L_ + l]) = pk;
            }
    } else {
#pragma unroll
        for (int mt = 0; mt < 4; ++mt)
#pragma unroll
            for (int nt = 0; nt < 4; ++nt)
#pragma unroll
                for (int reg = 0; reg < 4; ++reg) {
                    int rr = m0 + (wm << 6) + (mt << 4) + rq + reg;
                    int cc = n0 + (wn << 6) + (nt << 4) + col;
                    C[(size_t)rr * ldc + cc] = (OutT)acc[mt][nt][reg];
                }
    }
}

// ------------- causal flash attention v4: swapped QK^T, 32x32 MFMA, in-reg softmax ----
// qk:  [B*L][2048]  (Q at col 0, K at col 1024; head h at +h*64)
// vt:  [B][H][HD][L]  (V transposed)
// O:   [B*L][1024]
// 4 waves/block, wave owns 32 q rows; block = 128 q rows. No LDS in main loop.
__global__ __launch_bounds__(256) void attn_kernel(const bf16* __restrict__ qk,
                                                   const bf16* __restrict__ vt,
                                                   bf16* __restrict__ O) {
    __shared__ bf16 Olds[4][32][72];  // per-wave O-transpose buffer (epilogue only)
    const int nbh = B_ * H_;  // 32
    const int qt = (L_ / 128) - 1 - (int)(blockIdx.x / nbh);  // heavy tiles first
    const int bh = blockIdx.x % nbh;
    const int h = bh % H_, b = bh / H_;
    const int t = threadIdx.x, lane = t & 63, w = t >> 6;
    const int li = lane & 31, hi = lane >> 5;
    const int qg0 = qt * 128 + w * 32;   // wave's first q row
    const int q_g = qg0 + li;            // this lane's q column

    const bf16* kbase = qk + (size_t)b * L_ * QK_LD + D_ + h * HD_;
    const bf16* vbase = vt + (size_t)bh * HD_ * L_;

    // Q as B-operand: col = li (q), k = c*16 + hi*8 + i (hd)
    const bf16* qrow_p = qk + (size_t)(b * L_ + q_g) * QK_LD + h * HD_ + hi * 8;
    bf16x8 qB[4];
#pragma unroll
    for (int c = 0; c < 4; ++c) qB[c] = *reinterpret_cast<const bf16x8*>(qrow_p + c * 16);

    f32x16 ot0 = {}, ot1 = {};  // O^T accum: rows hd 0-31 / 32-63, col q=li
    float mrun = -1e30f, lsum = 0.f;
    const float c1 = 0.18033688011112042f;  // (1/8) * log2(e)

    const int nkb = (qg0 + 31) / 64 + 1;
    for (int kb = 0; kb < nkb; ++kb) {
        const int c0 = kb * 64;
        // ---- QK^T (swapped): st = K_tile . Q^T -> S^T[kv][q] ----
        f32x16 st0 = {}, st1 = {};
        const bf16* kp0 = kbase + (size_t)(c0 + li) * QK_LD + hi * 8;
        const bf16* kp1 = kbase + (size_t)(c0 + 32 + li) * QK_LD + hi * 8;
#pragma unroll
        for (int c = 0; c < 4; ++c) {
            st0 = mfma_32x32x16(*reinterpret_cast<const bf16x8*>(kp0 + c * 16), qB[c], st0);
            st1 = mfma_32x32x16(*reinterpret_cast<const bf16x8*>(kp1 + c * 16), qB[c], st1);
        }
        // ---- mask + scale (log2 domain), in-lane row max ----
        float rm = -1e30f;
#pragma unroll
        for (int r = 0; r < 16; ++r) {
            const int kvl = (r & 3) + 8 * (r >> 2) + 4 * hi;
            float x0 = (c0 + kvl <= q_g) ? st0[r] * c1 : -1e30f;
            float x1 = (c0 + 32 + kvl <= q_g) ? st1[r] * c1 : -1e30f;
            st0[r] = x0; st1[r] = x1;
            rm = fmaxf(rm, fmaxf(x0, x1));
        }
        rm = fmaxf(rm, __shfl_xor(rm, 32));  // full 32-kv row max (both halves)
        const float mn = fmaxf(mrun, rm);
        if (!__all(rm - mrun <= 8.0f)) {  // defer-max (T13)
            const float sc = exp2f(mrun - mn);
            lsum *= sc;
#pragma unroll
            for (int r = 0; r < 16; ++r) { ot0[r] *= sc; ot1[r] *= sc; }
            mrun = mn;
        }
        // ---- p = 2^(xs - m), in-lane row sum ----
        float rs = 0.f;
#pragma unroll
        for (int r = 0; r < 16; ++r) {
            float p0 = exp2f(st0[r] - mrun);
            float p1 = exp2f(st1[r] - mrun);
            st0[r] = p0; st1[r] = p1;
            rs += p0 + p1;
        }
        rs += __shfl_xor(rs, 32);
        lsum += rs;
        // ---- pack P^T to bf16 words, exchange across lane halves ----
        uint32_t wa[8], wb[8], ea[8], eb[8];
#pragma unroll
        for (int k = 0; k < 8; ++k) {
            asm("v_cvt_pk_bf16_f32 %0, %1, %2" : "=v"(wa[k]) : "v"(st0[2 * k]), "v"(st0[2 * k + 1]));
            asm("v_cvt_pk_bf16_f32 %0, %1, %2" : "=v"(wb[k]) : "v"(st1[2 * k]), "v"(st1[2 * k + 1]));
        }
#pragma unroll
        for (int k = 0; k < 8; ++k) {
            ea[k] = (uint32_t)__shfl_xor((int)wa[k], 32);
            eb[k] = (uint32_t)__shfl_xor((int)wb[k], 32);
        }
        // ---- assemble PV B-fragments: pb[j] covers kv c0+j*16..+16 ----
        union U8 { uint32_t u[4]; bf16x8 v; };
        U8 pb[4];
        pb[0].u[0] = hi ? ea[2] : wa[0]; pb[0].u[1] = hi ? ea[3] : wa[1];
        pb[0].u[2] = hi ? wa[2] : ea[0]; pb[0].u[3] = hi ? wa[3] : ea[1];
        pb[1].u[0] = hi ? ea[6] : wa[4]; pb[1].u[1] = hi ? ea[7] : wa[5];
        pb[1].u[2] = hi ? wa[6] : ea[4]; pb[1].u[3] = hi ? wa[7] : ea[5];
        pb[2].u[0] = hi ? eb[2] : wb[0]; pb[2].u[1] = hi ? eb[3] : wb[1];
        pb[2].u[2] = hi ? wb[2] : eb[0]; pb[2].u[3] = hi ? wb[3] : eb[1];
        pb[3].u[0] = hi ? eb[6] : wb[4]; pb[3].u[1] = hi ? eb[7] : wb[5];
        pb[3].u[2] = hi ? wb[6] : eb[4]; pb[3].u[3] = hi ? wb[7] : eb[5];
        // ---- PV: O^T += V^T . P^T ----
        const bf16* vp0 = vbase + (size_t)li * L_ + c0 + hi * 8;
        const bf16* vp1 = vbase + (size_t)(32 + li) * L_ + c0 + hi * 8;
#pragma unroll
        for (int j = 0; j < 4; ++j) {
            ot0 = mfma_32x32x16(*reinterpret_cast<const bf16x8*>(vp0 + j * 16), pb[j].v, ot0);
            ot1 = mfma_32x32x16(*reinterpret_cast<const bf16x8*>(vp1 + j * 16), pb[j].v, ot1);
        }
    }
    // ---- epilogue: normalize, transpose via LDS, coalesced store ----
    const float rinv = 1.0f / lsum;
#pragma unroll
    for (int r2 = 0; r2 < 8; ++r2) {
        const int hd0 = 2 * (r2 & 1) + 8 * (r2 >> 1) + 4 * hi;
        uint32_t u0, u1;
        float a0 = ot0[2 * r2] * rinv, a1 = ot0[2 * r2 + 1] * rinv;
        float b0 = ot1[2 * r2] * rinv, b1 = ot1[2 * r2 + 1] * rinv;
        asm("v_cvt_pk_bf16_f32 %0, %1, %2" : "=v"(u0) : "v"(a0), "v"(a1));
        asm("v_cvt_pk_bf16_f32 %0, %1, %2" : "=v"(u1) : "v"(b0), "v"(b1));
        *reinterpret_cast<uint32_t*>(&Olds[w][li][hd0]) = u0;
        *reinterpret_cast<uint32_t*>(&Olds[w][li][32 + hd0]) = u1;
    }
    __syncthreads();  // cross-lane LDS visibility
    const int qr = lane >> 1, half = lane & 1;
    const size_t orow = ((size_t)b * L_ + qt * 128 + w * 32 + qr) * D_ + h * HD_ + half * 32;
#pragma unroll
    for (int k = 0; k < 4; ++k) {
        bf16x8 vv = *reinterpret_cast<const bf16x8*>(&Olds[w][qr][half * 32 + k * 8]);
        *reinterpret_cast<bf16x8*>(&O[orow + k * 8]) = vv;
    }
}

extern "C" void kernel_launch(void* const* d_in, const int* in_sizes, int n_in,
                              void* d_out, int out_size, void* d_ws, size_t ws_size,
                              hipStream_t stream) {
    // setup_inputs dict order: x, Wk, Wq, Wv, Wo
    const float* x = (const float*)d_in[0];
    const float* Wk = (const float*)d_in[1];
    const float* Wq = (const float*)d_in[2];
    const float* Wv = (const float*)d_in[3];
    const float* Wo = (const float*)d_in[4];
    float* out = (float*)d_out;

    char* p = (char*)d_ws;
    const size_t xsz = (size_t)ML_ * D_ * sizeof(bf16);   // 8 MB
    const size_t wsz = (size_t)D_ * D_ * sizeof(bf16);    // 2 MB
    bf16* xb = (bf16*)p;   p += xsz;                      // x bf16 [4096][1024]
    bf16* Wc = (bf16*)p;   p += 3 * wsz;                  // [Wq^T; Wk^T; Wv^T] rows
    bf16* Wot = (bf16*)p;  p += wsz;
    bf16* qkb = (bf16*)p;  p += (size_t)ML_ * QK_LD * sizeof(bf16);  // [4096][2048] Q|K
    bf16* vtb = (bf16*)p;  p += xsz;                      // [B][H][HD][L] = 8 MB
    bf16* ab = xb;  // attn output reuses x buffer (x dead after qkv GEMM)

    const int n4 = ML_ * D_ / 4;
    cast_x_kernel<<<(n4 + 255) / 256, 256, 0, stream>>>(x, xb, n4);
    dim3 tb(32, 32);
    dim3 tg(D_ / 32, D_ / 32);
    transpose_w_kernel<<<tg, tb, 0, stream>>>(Wq, Wc);
    transpose_w_kernel<<<tg, tb, 0, stream>>>(Wk, Wc + (size_t)D_ * D_);
    transpose_w_kernel<<<tg, tb, 0, stream>>>(Wv, Wc + 2 * (size_t)D_ * D_);
    transpose_w_kernel<<<tg, tb, 0, stream>>>(Wo, Wot);

    // fused QKV projection: Q,K -> qkb (stride 2048); V -> vtb transposed
    gemm128_kernel<bf16><<<(ML_ / 128) * (S_ / 128), 256, 0, stream>>>(
        xb, Wc, qkb, vtb, ML_, S_, D_, QK_LD);

    attn_kernel<<<B_ * H_ * (L_ / 128), 256, 0, stream>>>(qkb, vtb, ab);

    // output projection -> fp32 out
    gemm128_kernel<float><<<(ML_ / 128) * (D_ / 128), 256, 0, stream>>>(
        ab, Wot, out, nullptr, ML_, D_, D_, D_);
}